// Round 10
// baseline (1277.821 us; speedup 1.0000x reference)
//
#include <hip/hip_runtime.h>
#include <hip/hip_fp16.h>

#define BB 512
#define TT 512
#define EE 100
#define HH 40
#define GG 120   // 3*HH
#define TC 64    // timesteps per chunk
#define NC 8     // chunks

typedef _Float16 h2_t __attribute__((ext_vector_type(2)));

__device__ __forceinline__ float fdot2_(h2_t a, h2_t b, float c) {
    return __builtin_amdgcn_fdot2(a, b, c, false);
}
__device__ __forceinline__ h2_t pack2_(float x, float y) {
    h2_t r; r[0] = (_Float16)x; r[1] = (_Float16)y; return r;
}
__device__ __forceinline__ float sigmoid_(float x) {
    return 1.0f / (1.0f + __expf(-x));
}
__device__ __forceinline__ float tanhfast_(float x) {
    float e = __expf(2.0f * x);
    return 1.0f - 2.0f / (e + 1.0f);
}

// rank batches by len desc -> perm[rank] = batch. One block, once per call.
__global__ __launch_bounds__(BB) void rank_kernel(const int* __restrict__ lens,
                                                  int* __restrict__ perm) {
    __shared__ int L[BB];
    const int i = threadIdx.x;
    L[i] = lens[i];
    __syncthreads();
    const int li = L[i];
    int r = 0;
    for (int jj = 0; jj < BB; ++jj) {
        const int lj = L[jj];
        r += (lj > li) || (lj == li && jj < i);
    }
    perm[r] = i;
}

// Round-10: PHASE-SHIFTED 2-chain scan. A wave runs two same-dir chains
// (rank-adjacent batches -> similar len -> both active together; weights
// SHARED, 60 VGPRs). Program order per step: [A: gates->hn->ds_write->
// 5x ds_read prefetch] then [B: same]. A's LDS round-trip (~280cyc) elapses
// under B's compute (~350cyc) and vice versa — the round-trip leaves the
// critical path (r7 failed because both chains' round-trips were IN phase).
// launch_bounds(256,1): VGPR cap 256 -> ~140-reg scan wave stays resident.
// GEMM half unchanged from r9 (prio 0, early-out past len).
template<int K, bool GATHER>
__global__ __launch_bounds__(256, 1) void fused_kernel(
    const int cg, const int cs, const int nScan,
    const int* __restrict__ perm,
    const int* __restrict__ text, const float* __restrict__ emb,
    const __half* __restrict__ Xh,
    const float* __restrict__ Wf, const float* __restrict__ bf,
    const float* __restrict__ Wb, const float* __restrict__ bb,
    __half* __restrict__ gxW, const __half* __restrict__ gxR,
    const float* __restrict__ WhhF, const float* __restrict__ bhhF,
    const float* __restrict__ WhhB, const float* __restrict__ bhhB,
    const int* __restrict__ lens,
    __half* __restrict__ out0,
    float* __restrict__ hcar, float* __restrict__ hlast,
    float* __restrict__ sumb, float* __restrict__ maxb)
{
    constexpr int K2 = K / 2;
    __shared__ h2_t Xs2[K2 * 64];
    __shared__ h2_t Ws2[K2 * 64];
    __shared__ __align__(16) _Float16 hAs[4][48];
    __shared__ __align__(16) _Float16 hBs[4][48];
    const int tid = threadIdx.x;

    if ((int)blockIdx.x < nScan) {
        __builtin_amdgcn_s_setprio(3);
        const int w = tid >> 6, j = tid & 63;
        if (j >= HH) return;
        const int slot = blockIdx.x * 4 + w;    // 0..511
        const int dir = slot >> 8;
        const int pr  = slot & 255;
        const int bA = perm[2*pr], bB = perm[2*pr + 1];

        const float* Whh = dir ? WhhB : WhhF;
        const float* bhh = dir ? bhhB : bhhF;
        h2_t Wr[HH/2], Wz[HH/2], Wn[HH/2];   // shared by both chains
        {
            const float4* r4 = (const float4*)(Whh + (size_t)(0*HH + j) * HH);
            const float4* z4 = (const float4*)(Whh + (size_t)(1*HH + j) * HH);
            const float4* n4 = (const float4*)(Whh + (size_t)(2*HH + j) * HH);
            #pragma unroll
            for (int q = 0; q < HH/4; ++q) {
                float4 v;
                v = r4[q]; Wr[2*q] = pack2_(v.x,v.y); Wr[2*q+1] = pack2_(v.z,v.w);
                v = z4[q]; Wz[2*q] = pack2_(v.x,v.y); Wz[2*q+1] = pack2_(v.z,v.w);
                v = n4[q]; Wn[2*q] = pack2_(v.x,v.y); Wn[2*q+1] = pack2_(v.z,v.w);
            }
        }
        const float br = bhh[j], bz = bhh[HH + j], bn = bhh[2*HH + j];
        const int lenA = lens[bA], lenB = lens[bB];
        const int chunk = dir ? (NC - 1 - cs) : cs;
        const int tb = chunk * TC;

        // active ranges (wave-uniform; all executed steps have t < len)
        int aB, aE, bB2, bE;
        if (dir == 0) {
            aB = 0;  aE = min(TC, max(0, lenA - tb));
            bB2 = 0; bE = min(TC, max(0, lenB - tb));
        } else {
            aB = max(0, tb + TC - lenA);  aE = TC;
            bB2 = max(0, tb + TC - lenB); bE = TC;
        }
        const int lo = min(aB < aE ? aB : TC, bB2 < bE ? bB2 : TC);
        const int hi = max(aB < aE ? aE : 0,  bB2 < bE ? bE : 0);

        float hA = (cs == 0) ? 0.0f : hcar[(size_t)(dir*BB + bA) * HH + j];
        float hB = (cs == 0) ? 0.0f : hcar[(size_t)(dir*BB + bB) * HH + j];
        _Float16* hshA = hAs[w];
        _Float16* hshB = hBs[w];
        hshA[j] = (_Float16)hA;
        hshB[j] = (_Float16)hB;
        float4 haA[5], haB[5];
        {
            const float4* pA = (const float4*)hshA;
            const float4* pB = (const float4*)hshB;
            #pragma unroll
            for (int q = 0; q < 5; ++q) { haA[q] = pA[q]; haB[q] = pB[q]; }
        }
        float psA = 0.f, pmA = -3.4e38f, psB = 0.f, pmB = -3.4e38f;
        const size_t rowA = ((size_t)dir * BB + bA) * TC;
        const size_t rowB = ((size_t)dir * BB + bB) * TC;

        // initial gx (1-deep cur regs) for first active step of each chain
        __half crA = __float2half(0.f), czA = crA, cnA = crA;
        __half crB = crA, czB = crA, cnB = crA;
        if (aB < aE) {
            const int tl = dir ? (TC - 1 - aB) : aB;
            const __half* g = gxR + (rowA + tl) * GG;
            crA = g[j]; czA = g[HH + j]; cnA = g[2*HH + j];
        }
        if (bB2 < bE) {
            const int tl = dir ? (TC - 1 - bB2) : bB2;
            const __half* g = gxR + (rowB + tl) * GG;
            crB = g[j]; czB = g[HH + j]; cnB = g[2*HH + j];
        }

        #define SCAN_HALF(bX, hX, haX, crX, czX, cnX, psX, pmX, hshX, xB, xE, rowX) \
        if (s >= (xB) && s < (xE)) {                                               \
            const int tloc = dir ? (TC - 1 - s) : s;                               \
            const float gr = __half2float(crX);                                    \
            const float gz = __half2float(czX);                                    \
            const float gn = __half2float(cnX);                                    \
            if (s + 1 < (xE)) {                                                    \
                const int tn = dir ? (TC - 2 - s) : (s + 1);                       \
                const __half* gq = gxR + ((rowX) + tn) * GG;                       \
                crX = gq[j]; czX = gq[HH + j]; cnX = gq[2*HH + j];                 \
            }                                                                      \
            float r0 = br, r1 = 0.f, z0 = bz, z1 = 0.f, n0 = bn, n1 = 0.f;        \
            _Pragma("unroll")                                                      \
            for (int q = 0; q < 5; ++q) {                                          \
                union { float4 f; h2_t h[4]; } u;                                  \
                u.f = haX[q];                                                      \
                r0 = fdot2_(Wr[4*q+0], u.h[0], r0);                                \
                z0 = fdot2_(Wz[4*q+0], u.h[0], z0);                                \
                n0 = fdot2_(Wn[4*q+0], u.h[0], n0);                                \
                r1 = fdot2_(Wr[4*q+1], u.h[1], r1);                                \
                z1 = fdot2_(Wz[4*q+1], u.h[1], z1);                                \
                n1 = fdot2_(Wn[4*q+1], u.h[1], n1);                                \
                r0 = fdot2_(Wr[4*q+2], u.h[2], r0);                                \
                z0 = fdot2_(Wz[4*q+2], u.h[2], z0);                                \
                n0 = fdot2_(Wn[4*q+2], u.h[2], n0);                                \
                r1 = fdot2_(Wr[4*q+3], u.h[3], r1);                                \
                z1 = fdot2_(Wz[4*q+3], u.h[3], z1);                                \
                n1 = fdot2_(Wn[4*q+3], u.h[3], n1);                                \
            }                                                                      \
            const float rr = sigmoid_(gr + r0 + r1);                               \
            const float zz = sigmoid_(gz + z0 + z1);                               \
            const float nn = tanhfast_(gn + rr * (n0 + n1));                       \
            const float hn = (1.0f - zz) * nn + zz * hX;                           \
            hX = hn;                                                               \
            hshX[j] = (_Float16)hn;        /* ds_write, then prefetch reads */     \
            {                                                                      \
                const float4* hp = (const float4*)hshX;                            \
                haX[0] = hp[0]; haX[1] = hp[1]; haX[2] = hp[2];                    \
                haX[3] = hp[3]; haX[4] = hp[4];                                    \
            }                                                                      \
            if (GATHER) {                                                          \
                const int t_ = tb + tloc;                                          \
                out0[((size_t)(bX)*TT + t_)*(2*HH) + dir*HH + j] =                 \
                    __float2half(hn);                                              \
            } else {                                                               \
                psX += hn; pmX = fmaxf(pmX, hn);                                   \
            }                                                                      \
        }

        for (int s = lo; s < hi; ++s) {
            SCAN_HALF(bA, hA, haA, crA, czA, cnA, psA, pmA, hshA, aB, aE, rowA)
            SCAN_HALF(bB, hB, haB, crB, czB, cnB, psB, pmB, hshB, bB2, bE, rowB)
        }
        #undef SCAN_HALF

        hcar[(size_t)(dir*BB + bA) * HH + j] = hA;
        hcar[(size_t)(dir*BB + bB) * HH + j] = hB;
        const int layer = GATHER ? 0 : 1;
        if (cs == NC - 1) {
            hlast[((size_t)(layer*2 + dir) * BB + bA) * HH + j] = hA;
            hlast[((size_t)(layer*2 + dir) * BB + bB) * HH + j] = hB;
        }
        if (!GATHER) {
            const size_t pA = (size_t)bA * (2*HH) + dir*HH + j;
            const size_t pB = (size_t)bB * (2*HH) + dir*HH + j;
            if (cs == 0) { sumb[pA] = psA; maxb[pA] = pmA;
                           sumb[pB] = psB; maxb[pB] = pmB; }
            else { sumb[pA] += psA; maxb[pA] = fmaxf(maxb[pA], pmA);
                   sumb[pB] += psB; maxb[pB] = fmaxf(maxb[pB], pmB); }
        }
        return;
    }

    // ================= gemm (fp16 dot2), prio 0 — unchanged from r9 ========
    __builtin_amdgcn_s_setprio(0);
    const int gid = blockIdx.x - nScan;
    const int b   = gid & (BB - 1);
    const int ct  = (gid >> 9) & 1;
    const int dir = gid >> 10;
    const int chunk = dir ? (NC - 1 - cg) : cg;
    const int tbase = chunk * TC;
    if (tbase >= lens[b]) return;   // tile fully past len: gx never read
    const float* W    = dir ? Wb : Wf;
    const float* bias = dir ? bb : bf;
    const int c0 = ct * 64;

    if (GATHER) {
        constexpr int KQ = K / 4;
        for (int idx = tid; idx < 64 * KQ; idx += 256) {
            const int r = idx & 63, q = idx >> 6;
            const int tok = text[b * TT + tbase + r];
            const float4 v = ((const float4*)emb)[(size_t)tok * KQ + q];
            Xs2[(2*q+0)*64 + r] = pack2_(v.x, v.y);
            Xs2[(2*q+1)*64 + r] = pack2_(v.z, v.w);
        }
    } else {
        constexpr int KQ8 = K / 8;
        for (int idx = tid; idx < 64 * KQ8; idx += 256) {
            const int r = idx & 63, q = idx >> 6;
            union { float4 f; h2_t h[4]; } u;
            u.f = ((const float4*)Xh)[((size_t)b * TT + tbase + r) * KQ8 + q];
            #pragma unroll
            for (int i2 = 0; i2 < 4; ++i2)
                Xs2[(4*q + i2)*64 + r] = u.h[i2];
        }
    }
    {
        constexpr int KQ = K / 4;
        for (int idx = tid; idx < 64 * KQ; idx += 256) {
            const int c = idx & 63, q = idx >> 6;
            float4 v = make_float4(0.f,0.f,0.f,0.f);
            if (c0 + c < GG) v = ((const float4*)W)[(size_t)(c0 + c) * KQ + q];
            Ws2[(2*q+0)*64 + c] = pack2_(v.x, v.y);
            Ws2[(2*q+1)*64 + c] = pack2_(v.z, v.w);
        }
    }
    __syncthreads();

    const int tx = tid & 15, ty = tid >> 4;
    float acc[4][4] = {};
    #pragma unroll 2
    for (int k2 = 0; k2 < K2; ++k2) {
        union { float4 f; h2_t h[4]; } xa, wv;
        xa.f = *(const float4*)(Xs2 + k2*64 + (ty << 2));
        wv.f = *(const float4*)(Ws2 + k2*64 + (tx << 2));
        #pragma unroll
        for (int i = 0; i < 4; ++i)
            #pragma unroll
            for (int j2 = 0; j2 < 4; ++j2)
                acc[i][j2] = fdot2_(xa.h[i], wv.h[j2], acc[i][j2]);
    }

    const int c = c0 + (tx << 2);
    if (c < GG) {
        const float b0v = bias[c], b1v = bias[c+1], b2v = bias[c+2], b3v = bias[c+3];
        const size_t rowB = ((size_t)dir * BB + b) * TC;
        #pragma unroll
        for (int i = 0; i < 4; ++i) {
            const int tloc = (ty << 2) + i;
            union { float2 f; __half2 h[2]; } u;
            u.h[0] = __floats2half2_rn(acc[i][0] + b0v, acc[i][1] + b1v);
            u.h[1] = __floats2half2_rn(acc[i][2] + b2v, acc[i][3] + b3v);
            *(float2*)(gxW + (rowB + tloc) * GG + c) = u.f;
        }
    }
}

// pool_cat = [hb1, hf1, hb0, hf0, avg(80), max(80)] -> fc1(128) -> lrelu -> fc2(1)
__global__ __launch_bounds__(128) void fc_kernel(
    const float* __restrict__ hlast, const float* __restrict__ sumb,
    const float* __restrict__ maxb, const int* __restrict__ lens,
    const float* __restrict__ fc1W, const float* __restrict__ fc1b,
    const float* __restrict__ fc2W, const float* __restrict__ fc2b,
    float* __restrict__ out)
{
    __shared__ float pool[8 * HH];
    __shared__ float red[128];
    const int b = blockIdx.x, tid = threadIdx.x;
    if (tid < HH) {
        pool[tid]        = hlast[(size_t)(3*BB + b) * HH + tid]; // hb1
        pool[HH + tid]   = hlast[(size_t)(2*BB + b) * HH + tid]; // hf1
        pool[2*HH + tid] = hlast[(size_t)(1*BB + b) * HH + tid]; // hb0
        pool[3*HH + tid] = hlast[(size_t)(0*BB + b) * HH + tid]; // hf0
    }
    const float invLen = 1.0f / (float)lens[b];
    if (tid < 2*HH) {
        pool[4*HH + tid] = sumb[(size_t)b * 2*HH + tid] * invLen;
        pool[6*HH + tid] = maxb[(size_t)b * 2*HH + tid];
    }
    __syncthreads();
    float acc = fc1b[tid];
    for (int k = 0; k < 8*HH; ++k)
        acc = fmaf(pool[k], fc1W[(size_t)tid * (8*HH) + k], acc);
    float v = (acc >= 0.0f) ? acc : 0.01f * acc;
    red[tid] = v * fc2W[tid];
    __syncthreads();
    for (int s = 64; s > 0; s >>= 1) {
        if (tid < s) red[tid] += red[tid + s];
        __syncthreads();
    }
    if (tid == 0) out[b] = red[0] + fc2b[0];
}

extern "C" void kernel_launch(void* const* d_in, const int* in_sizes, int n_in,
                              void* d_out, int out_size, void* d_ws, size_t ws_size,
                              hipStream_t stream) {
    const int*   text  = (const int*)d_in[0];
    const int*   lens  = (const int*)d_in[1];
    const float* emb   = (const float*)d_in[2];
    const float* Wih0f = (const float*)d_in[3];
    const float* Whh0f = (const float*)d_in[4];
    const float* bih0f = (const float*)d_in[5];
    const float* bhh0f = (const float*)d_in[6];
    const float* Wih0b = (const float*)d_in[7];
    const float* Whh0b = (const float*)d_in[8];
    const float* bih0b = (const float*)d_in[9];
    const float* bhh0b = (const float*)d_in[10];
    const float* Wih1f = (const float*)d_in[11];
    const float* Whh1f = (const float*)d_in[12];
    const float* bih1f = (const float*)d_in[13];
    const float* bhh1f = (const float*)d_in[14];
    const float* Wih1b = (const float*)d_in[15];
    const float* Whh1b = (const float*)d_in[16];
    const float* bih1b = (const float*)d_in[17];
    const float* bhh1b = (const float*)d_in[18];
    const float* fc1W  = (const float*)d_in[19];
    const float* fc1b  = (const float*)d_in[20];
    const float* fc2W  = (const float*)d_in[21];
    const float* fc2b  = (const float*)d_in[22];
    float* out = (float*)d_out;

    // ws: gx double-buffer fp16 (2 x 15.73MB) | out0 fp16 (41.94MB) | small
    char* p = (char*)d_ws;
    const size_t gxB = (size_t)2 * BB * TC * GG * sizeof(__half);
    __half* gxb0  = (__half*)p;  p += gxB;
    __half* gxb1  = (__half*)p;  p += gxB;
    __half* out0  = (__half*)p;  p += (size_t)BB * TT * 2 * HH * sizeof(__half);
    float*  hcar  = (float*)p;   p += (size_t)2 * BB * HH * sizeof(float);
    float*  hlast = (float*)p;   p += (size_t)4 * BB * HH * sizeof(float);
    float*  sumb  = (float*)p;   p += (size_t)BB * 2 * HH * sizeof(float);
    float*  maxb  = (float*)p;   p += (size_t)BB * 2 * HH * sizeof(float);
    int*    perm  = (int*)p;
    __half* gxb[2] = { gxb0, gxb1 };

    const int NG = BB * 2 * 2;   // 2048 gemm blocks
    const int NS = 128;          // 512 wave-slots (256 pairs x 2 dirs) / 4

    rank_kernel<<<1, BB, 0, stream>>>(lens, perm);

    // ---- layer 0 ----
    fused_kernel<EE, true><<<NG, 256, 0, stream>>>(0, 0, 0, perm,
        text, emb, nullptr, Wih0f, bih0f, Wih0b, bih0b,
        gxb[0], gxb[0], Whh0f, bhh0f, Whh0b, bhh0b,
        lens, out0, hcar, hlast, sumb, maxb);
    for (int ci = 1; ci < NC; ++ci)
        fused_kernel<EE, true><<<NS + NG, 256, 0, stream>>>(ci, ci - 1, NS, perm,
            text, emb, nullptr, Wih0f, bih0f, Wih0b, bih0b,
            gxb[ci & 1], gxb[(ci - 1) & 1], Whh0f, bhh0f, Whh0b, bhh0b,
            lens, out0, hcar, hlast, sumb, maxb);
    fused_kernel<EE, true><<<NS, 256, 0, stream>>>(0, NC - 1, NS, perm,
        text, emb, nullptr, Wih0f, bih0f, Wih0b, bih0b,
        gxb[0], gxb[(NC - 1) & 1], Whh0f, bhh0f, Whh0b, bhh0b,
        lens, out0, hcar, hlast, sumb, maxb);

    // ---- layer 1 ----
    fused_kernel<2*HH, false><<<NG, 256, 0, stream>>>(0, 0, 0, perm,
        text, emb, out0, Wih1f, bih1f, Wih1b, bih1b,
        gxb[0], gxb[0], Whh1f, bhh1f, Whh1b, bhh1b,
        lens, out0, hcar, hlast, sumb, maxb);
    for (int ci = 1; ci < NC; ++ci)
        fused_kernel<2*HH, false><<<NS + NG, 256, 0, stream>>>(ci, ci - 1, NS, perm,
            text, emb, out0, Wih1f, bih1f, Wih1b, bih1b,
            gxb[ci & 1], gxb[(ci - 1) & 1], Whh1f, bhh1f, Whh1b, bhh1b,
            lens, out0, hcar, hlast, sumb, maxb);
    fused_kernel<2*HH, false><<<NS, 256, 0, stream>>>(0, NC - 1, NS, perm,
        text, emb, out0, Wih1f, bih1f, Wih1b, bih1b,
        gxb[0], gxb[(NC - 1) & 1], Whh1f, bhh1f, Whh1b, bhh1b,
        lens, out0, hcar, hlast, sumb, maxb);

    // ---- head ----
    fc_kernel<<<BB, 128, 0, stream>>>(hlast, sumb, maxb, lens,
        fc1W, fc1b, fc2W, fc2b, out);
}

// Round 11
// 753.873 us; speedup vs baseline: 1.6950x; 1.6950x over previous
//
#include <hip/hip_runtime.h>
#include <hip/hip_fp16.h>

#define BB 512
#define TT 512
#define EE 100
#define HH 40
#define GG 120   // 3*HH
#define TC 64    // timesteps per chunk
#define NC 8     // chunks

typedef _Float16 h2_t __attribute__((ext_vector_type(2)));

__device__ __forceinline__ float fdot2_(h2_t a, h2_t b, float c) {
    return __builtin_amdgcn_fdot2(a, b, c, false);
}
__device__ __forceinline__ h2_t pack2_(float x, float y) {
    h2_t r; r[0] = (_Float16)x; r[1] = (_Float16)y; return r;
}
__device__ __forceinline__ float sigmoid_(float x) {
    return 1.0f / (1.0f + __expf(-x));
}
__device__ __forceinline__ float tanhfast_(float x) {
    float e = __expf(2.0f * x);
    return 1.0f - 2.0f / (e + 1.0f);
}

// Round-11 = r9 (best, 730us) + three step-cycle cuts:
//  (1) scan: ds_write h THEN immediately ds_read 5xb128 into registers
//      (ha[5]); the ~150cyc LDS round-trip elapses under the step tail
//      (out0 store / pooling / gx cvt / bookkeeping) instead of stalling
//      the next step's dot block at a cold lgkmcnt(0). Single chain per
//      wave (minimizes wall; r10's pairing doubled the wall).
//  (2) hn = fma(z, h-n, n) — shorter gate tail.
//  (3) GEMM: 64x128 tile (4x8 micro-tile, W staged once per 128 cols) —
//      ~30% fewer GEMM instructions -> more issue slots for scan waves.
// Kept from r9: setprio 3/0, length-based step range (all executed steps
// valid), GEMM early-out past len, fp16 Whh in 60 resident VGPRs under
// __launch_bounds__(256,2), gx double-buffer.
template<int K, bool GATHER>
__global__ __launch_bounds__(256, 2) void fused_kernel(
    const int cg, const int cs, const int nScan,
    const int* __restrict__ text, const float* __restrict__ emb,
    const __half* __restrict__ Xh,
    const float* __restrict__ Wf, const float* __restrict__ bf,
    const float* __restrict__ Wb, const float* __restrict__ bb,
    __half* __restrict__ gxW, const __half* __restrict__ gxR,
    const float* __restrict__ WhhF, const float* __restrict__ bhhF,
    const float* __restrict__ WhhB, const float* __restrict__ bhhB,
    const int* __restrict__ lens,
    __half* __restrict__ out0,
    float* __restrict__ hcar, float* __restrict__ hlast,
    float* __restrict__ sumb, float* __restrict__ maxb)
{
    constexpr int K2 = K / 2;
    __shared__ h2_t Xs2[K2 * 64];     // [k2][row]
    __shared__ h2_t Ws2[K2 * 128];    // [k2][col]
    __shared__ __align__(16) _Float16 hsh[4][48];
    const int tid = threadIdx.x;

    if ((int)blockIdx.x < nScan) {
        // ============ scan: one wave = one (batch,dir) chain ============
        __builtin_amdgcn_s_setprio(3);
        const int wave = tid >> 6, j = tid & 63;
        if (j >= HH) return;
        const int chain = blockIdx.x * 4 + wave;   // 0..1023
        const int dir = chain >> 9;
        const int b   = chain & (BB - 1);
        const float* Whh = dir ? WhhB : WhhF;
        const float* bhh = dir ? bhhB : bhhF;

        // Whh rows {j,40+j,80+j} packed half2: 60 VGPRs, resident
        h2_t Wr[HH/2], Wz[HH/2], Wn[HH/2];
        {
            const float4* r4 = (const float4*)(Whh + (size_t)(0*HH + j) * HH);
            const float4* z4 = (const float4*)(Whh + (size_t)(1*HH + j) * HH);
            const float4* n4 = (const float4*)(Whh + (size_t)(2*HH + j) * HH);
            #pragma unroll
            for (int q = 0; q < HH/4; ++q) {
                float4 v;
                v = r4[q]; Wr[2*q] = pack2_(v.x,v.y); Wr[2*q+1] = pack2_(v.z,v.w);
                v = z4[q]; Wz[2*q] = pack2_(v.x,v.y); Wz[2*q+1] = pack2_(v.z,v.w);
                v = n4[q]; Wn[2*q] = pack2_(v.x,v.y); Wn[2*q+1] = pack2_(v.z,v.w);
            }
        }
        const float br = bhh[j], bz = bhh[HH + j], bn = bhh[2*HH + j];
        const int len = lens[b];
        const int chunk = dir ? (NC - 1 - cs) : cs;
        const int tbase = chunk * TC;

        // executed step range: all executed steps have t < len
        int sBeg, sEnd;
        if (dir == 0) { sBeg = 0; sEnd = min(TC, max(0, len - tbase)); }
        else          { sBeg = max(0, tbase + TC - len); sEnd = TC; }

        float h = (cs == 0) ? 0.0f : hcar[(size_t)(dir * BB + b) * HH + j];
        hsh[wave][j] = (_Float16)h;
        float4 ha[5];
        {
            const float4* hp = (const float4*)hsh[wave];
            #pragma unroll
            for (int q = 0; q < 5; ++q) ha[q] = hp[q];
        }
        float psum = 0.0f, pmax = -3.4e38f;
        const size_t gxRow = ((size_t)dir * BB + b) * TC;

        __half rH = __float2half(0.f), zH = rH, nH = rH;
        if (sBeg < sEnd) {
            const int tl0 = dir ? (TC - 1 - sBeg) : sBeg;
            const __half* gp0 = gxR + (gxRow + tl0) * GG;
            rH = gp0[j]; zH = gp0[HH + j]; nH = gp0[2*HH + j];
        }

        for (int s = sBeg; s < sEnd; ++s) {
            const int tloc = dir ? (TC - 1 - s) : s;
            const int t = tbase + tloc;
            __half prH = __float2half(0.f), pzH = prH, pnH = prH;
            if (s + 1 < sEnd) {   // prefetch next step's gx
                const int tn = dir ? (TC - 2 - s) : (s + 1);
                const __half* gq = gxR + (gxRow + tn) * GG;
                prH = gq[j]; pzH = gq[HH + j]; pnH = gq[2*HH + j];
            }
            // GEMV: 60 dot2 over register h-cache (no LDS reads here)
            float r0 = br, r1 = 0.f, z0 = bz, z1 = 0.f, n0 = bn, n1 = 0.f;
            #pragma unroll
            for (int q = 0; q < 5; ++q) {
                union { float4 f; h2_t h[4]; } u;
                u.f = ha[q];
                r0 = fdot2_(Wr[4*q+0], u.h[0], r0);
                z0 = fdot2_(Wz[4*q+0], u.h[0], z0);
                n0 = fdot2_(Wn[4*q+0], u.h[0], n0);
                r1 = fdot2_(Wr[4*q+1], u.h[1], r1);
                z1 = fdot2_(Wz[4*q+1], u.h[1], z1);
                n1 = fdot2_(Wn[4*q+1], u.h[1], n1);
                r0 = fdot2_(Wr[4*q+2], u.h[2], r0);
                z0 = fdot2_(Wz[4*q+2], u.h[2], z0);
                n0 = fdot2_(Wn[4*q+2], u.h[2], n0);
                r1 = fdot2_(Wr[4*q+3], u.h[3], r1);
                z1 = fdot2_(Wz[4*q+3], u.h[3], z1);
                n1 = fdot2_(Wn[4*q+3], u.h[3], n1);
            }
            const float rr = sigmoid_(__half2float(rH) + r0 + r1);
            const float zz = sigmoid_(__half2float(zH) + z0 + z1);
            const float nn = tanhfast_(__half2float(nH) + rr * (n0 + n1));
            const float hn = fmaf(zz, h - nn, nn);   // (1-z)n + z h
            h = hn;
            // write h, then IMMEDIATELY read back into registers: the LDS
            // round-trip latency elapses under the step tail below.
            hsh[wave][j] = (_Float16)h;
            {
                const float4* hp = (const float4*)hsh[wave];
                ha[0] = hp[0]; ha[1] = hp[1]; ha[2] = hp[2];
                ha[3] = hp[3]; ha[4] = hp[4];
            }
            if (GATHER) {  // layer 0: materialize out0 fp16 (valid t only)
                out0[((size_t)b * TT + t) * (2*HH) + dir*HH + j] = __float2half(hn);
            } else {       // layer 1: fused pooling (valid t only)
                psum += hn;
                pmax = fmaxf(pmax, hn);
            }
            rH = prH; zH = pzH; nH = pnH;
        }
        hcar[(size_t)(dir * BB + b) * HH + j] = h;
        const int layer = GATHER ? 0 : 1;
        if (cs == NC - 1)
            hlast[((size_t)(layer * 2 + dir) * BB + b) * HH + j] = h;
        if (!GATHER) {
            const size_t pi = (size_t)b * (2*HH) + dir*HH + j;
            if (cs == 0) { sumb[pi] = psum;  maxb[pi] = pmax; }
            else         { sumb[pi] += psum; maxb[pi] = fmaxf(maxb[pi], pmax); }
        }
        return;
    }

    // ======== gemm: 64 rows x 128 cols (120 valid), 4x8 micro-tile ========
    __builtin_amdgcn_s_setprio(0);
    const int gid = blockIdx.x - nScan;
    const int b   = gid & (BB - 1);
    const int dir = gid >> 9;
    const int chunk = dir ? (NC - 1 - cg) : cg;
    const int tbase = chunk * TC;
    if (tbase >= lens[b]) return;   // tile fully past len: gx never read
    const float* W    = dir ? Wb : Wf;
    const float* bias = dir ? bb : bf;
    constexpr int KQ = K / 4;

    // stage X fp16 k-pair-major: Xs2[k2][r]
    if (GATHER) {
        for (int idx = tid; idx < 64 * KQ; idx += 256) {
            const int r = idx & 63, q = idx >> 6;
            const int tok = text[b * TT + tbase + r];
            const float4 v = ((const float4*)emb)[(size_t)tok * KQ + q];
            Xs2[(2*q+0)*64 + r] = pack2_(v.x, v.y);
            Xs2[(2*q+1)*64 + r] = pack2_(v.z, v.w);
        }
    } else {
        constexpr int KQ8 = K / 8;
        for (int idx = tid; idx < 64 * KQ8; idx += 256) {
            const int r = idx & 63, q = idx >> 6;
            union { float4 f; h2_t h[4]; } u;
            u.f = ((const float4*)Xh)[((size_t)b * TT + tbase + r) * KQ8 + q];
            #pragma unroll
            for (int i2 = 0; i2 < 4; ++i2)
                Xs2[(4*q + i2)*64 + r] = u.h[i2];
        }
    }
    // stage W fp16 k-pair-major: Ws2[k2][c], 120 valid cols padded to 128
    for (int idx = tid; idx < 128 * KQ; idx += 256) {
        const int c = idx & 127, q = idx >> 7;
        float4 v = make_float4(0.f, 0.f, 0.f, 0.f);
        if (c < GG) v = ((const float4*)W)[(size_t)c * KQ + q];
        Ws2[(2*q+0)*128 + c] = pack2_(v.x, v.y);
        Ws2[(2*q+1)*128 + c] = pack2_(v.z, v.w);
    }
    __syncthreads();

    const int tx = tid & 15, ty = tid >> 4;   // cols 8tx..+7, rows 4ty..+3
    float acc[4][8] = {};
    #pragma unroll 2
    for (int k2 = 0; k2 < K2; ++k2) {
        union { float4 f; h2_t h[4]; } xa, w0, w1;
        xa.f = *(const float4*)(Xs2 + k2*64  + (ty << 2));
        w0.f = *(const float4*)(Ws2 + k2*128 + (tx << 3));
        w1.f = *(const float4*)(Ws2 + k2*128 + (tx << 3) + 4);
        #pragma unroll
        for (int i = 0; i < 4; ++i) {
            #pragma unroll
            for (int j2 = 0; j2 < 4; ++j2) {
                acc[i][j2]     = fdot2_(xa.h[i], w0.h[j2], acc[i][j2]);
                acc[i][4 + j2] = fdot2_(xa.h[i], w1.h[j2], acc[i][4 + j2]);
            }
        }
    }

    if (tx < 15) {   // cols 120..127 invalid -> tx==15 discards
        const int c = tx << 3;
        float bv[8];
        #pragma unroll
        for (int j2 = 0; j2 < 8; ++j2) bv[j2] = bias[c + j2];
        const size_t rowB = ((size_t)dir * BB + b) * TC;
        #pragma unroll
        for (int i = 0; i < 4; ++i) {
            union { float4 f; __half2 h[4]; } u;
            #pragma unroll
            for (int j2 = 0; j2 < 4; ++j2)
                u.h[j2] = __floats2half2_rn(acc[i][2*j2] + bv[2*j2],
                                            acc[i][2*j2+1] + bv[2*j2+1]);
            *(float4*)(gxW + (rowB + (ty << 2) + i) * GG + c) = u.f;
        }
    }
}

// pool_cat = [hb1, hf1, hb0, hf0, avg(80), max(80)] -> fc1(128) -> lrelu -> fc2(1)
__global__ __launch_bounds__(128) void fc_kernel(
    const float* __restrict__ hlast, const float* __restrict__ sumb,
    const float* __restrict__ maxb, const int* __restrict__ lens,
    const float* __restrict__ fc1W, const float* __restrict__ fc1b,
    const float* __restrict__ fc2W, const float* __restrict__ fc2b,
    float* __restrict__ out)
{
    __shared__ float pool[8 * HH];
    __shared__ float red[128];
    const int b = blockIdx.x, tid = threadIdx.x;
    if (tid < HH) {
        pool[tid]        = hlast[(size_t)(3*BB + b) * HH + tid]; // hb1
        pool[HH + tid]   = hlast[(size_t)(2*BB + b) * HH + tid]; // hf1
        pool[2*HH + tid] = hlast[(size_t)(1*BB + b) * HH + tid]; // hb0
        pool[3*HH + tid] = hlast[(size_t)(0*BB + b) * HH + tid]; // hf0
    }
    const float invLen = 1.0f / (float)lens[b];
    if (tid < 2*HH) {
        pool[4*HH + tid] = sumb[(size_t)b * 2*HH + tid] * invLen;
        pool[6*HH + tid] = maxb[(size_t)b * 2*HH + tid];
    }
    __syncthreads();
    float acc = fc1b[tid];
    for (int k = 0; k < 8*HH; ++k)
        acc = fmaf(pool[k], fc1W[(size_t)tid * (8*HH) + k], acc);
    float v = (acc >= 0.0f) ? acc : 0.01f * acc;
    red[tid] = v * fc2W[tid];
    __syncthreads();
    for (int s = 64; s > 0; s >>= 1) {
        if (tid < s) red[tid] += red[tid + s];
        __syncthreads();
    }
    if (tid == 0) out[b] = red[0] + fc2b[0];
}

extern "C" void kernel_launch(void* const* d_in, const int* in_sizes, int n_in,
                              void* d_out, int out_size, void* d_ws, size_t ws_size,
                              hipStream_t stream) {
    const int*   text  = (const int*)d_in[0];
    const int*   lens  = (const int*)d_in[1];
    const float* emb   = (const float*)d_in[2];
    const float* Wih0f = (const float*)d_in[3];
    const float* Whh0f = (const float*)d_in[4];
    const float* bih0f = (const float*)d_in[5];
    const float* bhh0f = (const float*)d_in[6];
    const float* Wih0b = (const float*)d_in[7];
    const float* Whh0b = (const float*)d_in[8];
    const float* bih0b = (const float*)d_in[9];
    const float* bhh0b = (const float*)d_in[10];
    const float* Wih1f = (const float*)d_in[11];
    const float* Whh1f = (const float*)d_in[12];
    const float* bih1f = (const float*)d_in[13];
    const float* bhh1f = (const float*)d_in[14];
    const float* Wih1b = (const float*)d_in[15];
    const float* Whh1b = (const float*)d_in[16];
    const float* bih1b = (const float*)d_in[17];
    const float* bhh1b = (const float*)d_in[18];
    const float* fc1W  = (const float*)d_in[19];
    const float* fc1b  = (const float*)d_in[20];
    const float* fc2W  = (const float*)d_in[21];
    const float* fc2b  = (const float*)d_in[22];
    float* out = (float*)d_out;

    // ws: gx double-buffer fp16 (2 x 15.73MB) | out0 fp16 (41.94MB) | small
    char* p = (char*)d_ws;
    const size_t gxB = (size_t)2 * BB * TC * GG * sizeof(__half);
    __half* gxb0  = (__half*)p;  p += gxB;
    __half* gxb1  = (__half*)p;  p += gxB;
    __half* out0  = (__half*)p;  p += (size_t)BB * TT * 2 * HH * sizeof(__half);
    float*  hcar  = (float*)p;   p += (size_t)2 * BB * HH * sizeof(float);
    float*  hlast = (float*)p;   p += (size_t)4 * BB * HH * sizeof(float);
    float*  sumb  = (float*)p;   p += (size_t)BB * 2 * HH * sizeof(float);
    float*  maxb  = (float*)p;
    __half* gxb[2] = { gxb0, gxb1 };

    const int NG = BB * 2;   // 1024 gemm blocks (b x dir), 128-col tiles
    const int NS = 256;      // 1024 chains / 4 waves per block

    // ---- layer 0 ----
    fused_kernel<EE, true><<<NG, 256, 0, stream>>>(0, 0, 0,
        text, emb, nullptr, Wih0f, bih0f, Wih0b, bih0b,
        gxb[0], gxb[0], Whh0f, bhh0f, Whh0b, bhh0b,
        lens, out0, hcar, hlast, sumb, maxb);
    for (int ci = 1; ci < NC; ++ci)
        fused_kernel<EE, true><<<NS + NG, 256, 0, stream>>>(ci, ci - 1, NS,
            text, emb, nullptr, Wih0f, bih0f, Wih0b, bih0b,
            gxb[ci & 1], gxb[(ci - 1) & 1], Whh0f, bhh0f, Whh0b, bhh0b,
            lens, out0, hcar, hlast, sumb, maxb);
    fused_kernel<EE, true><<<NS, 256, 0, stream>>>(0, NC - 1, NS,
        text, emb, nullptr, Wih0f, bih0f, Wih0b, bih0b,
        gxb[0], gxb[(NC - 1) & 1], Whh0f, bhh0f, Whh0b, bhh0b,
        lens, out0, hcar, hlast, sumb, maxb);

    // ---- layer 1 ----
    fused_kernel<2*HH, false><<<NG, 256, 0, stream>>>(0, 0, 0,
        text, emb, out0, Wih1f, bih1f, Wih1b, bih1b,
        gxb[0], gxb[0], Whh1f, bhh1f, Whh1b, bhh1b,
        lens, out0, hcar, hlast, sumb, maxb);
    for (int ci = 1; ci < NC; ++ci)
        fused_kernel<2*HH, false><<<NS + NG, 256, 0, stream>>>(ci, ci - 1, NS,
            text, emb, out0, Wih1f, bih1f, Wih1b, bih1b,
            gxb[ci & 1], gxb[(ci - 1) & 1], Whh1f, bhh1f, Whh1b, bhh1b,
            lens, out0, hcar, hlast, sumb, maxb);
    fused_kernel<2*HH, false><<<NS, 256, 0, stream>>>(0, NC - 1, NS,
        text, emb, out0, Wih1f, bih1f, Wih1b, bih1b,
        gxb[0], gxb[(NC - 1) & 1], Whh1f, bhh1f, Whh1b, bhh1b,
        lens, out0, hcar, hlast, sumb, maxb);

    // ---- head ----
    fc_kernel<<<BB, 128, 0, stream>>>(hlast, sumb, maxb, lens,
        fc1W, fc1b, fc2W, fc2b, out);
}